// Round 19
// baseline (133.144 us; speedup 1.0000x reference)
//
#include <hip/hip_runtime.h>
#include <hip/hip_bf16.h>
#include <stdint.h>

#define B_  64
#define N_  576
#define D_  1024
#define K_  144
#define HW_ 24
#define DIST_THR_F 16.733200530681511f

using bf16x8 = __attribute__((ext_vector_type(8))) short;
using f32x4  = __attribute__((ext_vector_type(4))) float;

__device__ __forceinline__ unsigned short f2bf(float f) {
    unsigned u = __float_as_uint(f);
    u += 0x7fffu + ((u >> 16) & 1u);
    return (unsigned short)(u >> 16);
}

__device__ __forceinline__ void pack8(const float4 a, const float4 b, float& ss,
                                      unsigned short* __restrict__ dst) {
    ss += a.x*a.x + a.y*a.y + a.z*a.z + a.w*a.w
        + b.x*b.x + b.y*b.y + b.z*b.z + b.w*b.w;
    union { bf16x8 v; unsigned short u[8]; } pk;
    pk.u[0] = f2bf(a.x); pk.u[1] = f2bf(a.y); pk.u[2] = f2bf(a.z); pk.u[3] = f2bf(a.w);
    pk.u[4] = f2bf(b.x); pk.u[5] = f2bf(b.y); pk.u[6] = f2bf(b.z); pk.u[7] = f2bf(b.w);
    *reinterpret_cast<bf16x8*>(dst) = pk.v;
}

// ---------------- Kernel 1: token selection (one block per batch, standalone) -------
// Also zeroes the per-row weight-sum accumulator (graph-replay safe).
__global__ __launch_bounds__(256) void k_select(const float* __restrict__ metric,
                                                int* __restrict__ bench_idx,
                                                int* __restrict__ high,
                                                float* __restrict__ out_idx,
                                                float* __restrict__ rowsum) {
    __shared__ float sm[N_];
    __shared__ float sc[512];
    __shared__ int   si[512];
    __shared__ unsigned smask[18];
    __shared__ int   wpref[18];
    __shared__ float thr_s;
    int b = blockIdx.x, tid = threadIdx.x;
    for (int i = tid; i < N_; i += 256) sm[i] = metric[b * N_ + i];
    if (tid < 18) smask[tid] = 0u;
    if (tid < 144) rowsum[b * K_ + tid] = 0.f;
    __syncthreads();
    if (tid < 144) {
        int ry = tid / 12, rx = tid - ry * 12;
        int base = ry * 48 + rx * 2;
        float vv[4] = { sm[base], sm[base + 1], sm[base + 24], sm[base + 25] };
        int   tk[4] = { base, base + 1, base + 24, base + 25 };
        int a0 = 0;
#pragma unroll
        for (int j = 1; j < 4; j++) if (vv[j] > vv[a0]) a0 = j;
        int a1 = -1;
#pragma unroll
        for (int j = 0; j < 4; j++) {
            if (j == a0) continue;
            if (a1 < 0 || vv[j] > vv[a1]) a1 = j;
        }
        sc[2 * tid]     = vv[a0]; si[2 * tid]     = tk[a0];
        sc[2 * tid + 1] = vv[a1]; si[2 * tid + 1] = tk[a1];
    }
    for (int i = 288 + tid; i < 512; i += 256) { sc[i] = -1e30f; si[i] = 0x7fffffff; }
    __syncthreads();
    for (int k = 2; k <= 512; k <<= 1) {
        for (int j = k >> 1; j > 0; j >>= 1) {
#pragma unroll 2
            for (int t = tid; t < 512; t += 256) {
                int ixj = t ^ j;
                if (ixj > t) {
                    float s1 = sc[t], s2 = sc[ixj];
                    int   i1 = si[t], i2 = si[ixj];
                    bool before = (s1 > s2) || (s1 == s2 && i1 < i2);
                    bool up = ((t & k) == 0);
                    if (up ? !before : before) {
                        sc[t] = s2; sc[ixj] = s1; si[t] = i2; si[ixj] = i1;
                    }
                }
            }
            __syncthreads();
        }
    }
    if (tid == 0) {
        float qpos = 0.55f * 143.0f;
        float g = qpos - 78.0f;
        thr_s = sc[65] * (1.0f - g) + sc[64] * g;
    }
    if (tid < 144) atomicOr(&smask[si[tid] >> 5], 1u << (si[tid] & 31));
    __syncthreads();
    if (tid == 0) {
        int acc = 0;
        for (int w = 0; w < 18; w++) { wpref[w] = acc; acc += __popc(smask[w]); }
    }
    __syncthreads();
    if (tid < 144) {
        int tok = si[tid], w = tok >> 5;
        int rank = wpref[w] + __popc(smask[w] & ((1u << (tok & 31)) - 1u));
        bench_idx[b * K_ + rank] = tok;
        high[b * K_ + rank] = (sc[tid] >= thr_s) ? 1 : 0;
        out_idx[b * K_ + rank] = (float)tok;
    }
}

// ---------------- Kernel 2: sim GEMM DIRECT FROM F32 (cast+norms fused in) ----------
// ROUND-19: eliminates the 85-us prep pass. Round-12's proven 128-thr structure;
// staging loads f32 (2x float4 per 16B-bf16 chunk), packs to bf16 into swizzled LDS,
// accumulates per-chunk sum(x^2). Each block streams FULL rows (all 16 K-tiles), so
// the 8-lane slot-octet shfl reduction yields exact row norms; epilogue applies
// invA*invB*penalty (relu commutes with positive scales — verified algebra).
__global__ __launch_bounds__(128) void k_simf(const float* __restrict__ hs,
                                              const int* __restrict__ bench_idx,
                                              const int* __restrict__ high,
                                              unsigned short* __restrict__ bwn,
                                              float* __restrict__ rowsum) {
    __shared__ unsigned short SM[144 * 64];
    __shared__ float rsum[48];
    __shared__ float ssL[144];
    int bid  = blockIdx.x;
    int xcd  = bid & 7;
    int slot = bid >> 3;               // 0..143
    int s18  = slot % 18;
    int b    = (slot / 18) * 8 + xcd;
    int rt   = s18 / 6;                // row tile 0..2
    int ct   = s18 % 6;                // col tile 0..5
    int tid  = threadIdx.x;
    int w = tid >> 6, lane = tid & 63, g = lane >> 4, r16 = lane & 15;

    if (tid < 48) rsum[tid] = 0.f;

    const float* base = hs + (size_t)b * N_ * D_;

    // chunk q: row = (tid>>3)+16q, slot p = tid&7, logical 8-elem group l = p^(row&7)
    const float* gsrc[9];
    int dsoff[9];
#pragma unroll
    for (int q = 0; q < 9; q++) {
        int row = (tid >> 3) + 16 * q;  // 0..143
        int p   = tid & 7;
        int l   = p ^ (row & 7);
        int tok = (row < 48) ? bench_idx[b * K_ + rt * 48 + row] : (ct * 96 + (row - 48));
        gsrc[q]  = base + (size_t)tok * D_ + l * 8;
        dsoff[q] = row * 64 + p * 8;
    }

    float4 freg[9][2];
    float  ssp[9];
#pragma unroll
    for (int q = 0; q < 9; q++) {
        ssp[q] = 0.f;
        freg[q][0] = *(const float4*)(gsrc[q]);
        freg[q][1] = *(const float4*)(gsrc[q] + 4);
    }

    f32x4 acc[3][3] = {};

    for (int t = 0; t < 16; ++t) {
        // pack + ds_write tile t (accumulating sum x^2 from the f32 values)
#pragma unroll
        for (int q = 0; q < 9; q++) pack8(freg[q][0], freg[q][1], ssp[q], &SM[dsoff[q]]);
        __syncthreads();
        // prefetch tile t+1 (flies under the MFMA phase)
        if (t < 15) {
            int kb = (t + 1) * 64;
#pragma unroll
            for (int q = 0; q < 9; q++) {
                freg[q][0] = *(const float4*)(gsrc[q] + kb);
                freg[q][1] = *(const float4*)(gsrc[q] + kb + 4);
            }
        }
        // MFMA phase
#pragma unroll
        for (int h = 0; h < 2; h++) {
            int ks = h * 4 + g;
            bf16x8 af[3], bf[3];
#pragma unroll
            for (int mi = 0; mi < 3; mi++) {
                int row = mi * 16 + r16;                       // A region rows 0..47
                af[mi] = *(const bf16x8*)&SM[row * 64 + (ks ^ (row & 7)) * 8];
            }
#pragma unroll
            for (int nj = 0; nj < 3; nj++) {
                int row = 48 + w * 48 + nj * 16 + r16;         // B region rows 48..143
                bf[nj] = *(const bf16x8*)&SM[row * 64 + (ks ^ (row & 7)) * 8];
            }
#pragma unroll
            for (int mi = 0; mi < 3; mi++)
#pragma unroll
                for (int nj = 0; nj < 3; nj++)
                    acc[mi][nj] = __builtin_amdgcn_mfma_f32_16x16x32_bf16(af[mi], bf[nj], acc[mi][nj], 0, 0, 0);
        }
        __syncthreads();
    }

    // full-row sum(x^2): reduce over the 8-lane slot octet (same tid>>3, slots 0..7)
#pragma unroll
    for (int q = 0; q < 9; q++) {
#pragma unroll
        for (int m = 1; m <= 4; m <<= 1) ssp[q] += __shfl_xor(ssp[q], m, 64);
        if ((lane & 7) == 0) ssL[(tid >> 3) + 16 * q] = ssp[q];
    }
    __syncthreads();

    // epilogue: v = relu(acc)*invA*invB*pen; row-sum; write bwn (self=0, high rows=0)
    float invB3[3];
#pragma unroll
    for (int nj = 0; nj < 3; nj++)
        invB3[nj] = 1.0f / fmaxf(sqrtf(ssL[48 + w * 48 + nj * 16 + r16]), 1e-12f);
#pragma unroll
    for (int mi = 0; mi < 3; mi++) {
#pragma unroll
        for (int r = 0; r < 4; r++) {
            int il = mi * 16 + g * 4 + r;        // local row 0..47
            int i  = rt * 48 + il;
            int ti = bench_idx[b * K_ + i];
            int hi = high[b * K_ + i];
            float invA = 1.0f / fmaxf(sqrtf(ssL[il]), 1e-12f);
            int y1 = ti / HW_, x1 = ti % HW_;
            unsigned short* prow = bwn + (size_t)(b * K_ + i) * N_;
            float vals[3];
            float sum3 = 0.f;
#pragma unroll
            for (int nj = 0; nj < 3; nj++) {
                int col = ct * 96 + w * 48 + nj * 16 + r16;
                int y2 = col / HW_, x2 = col % HW_;
                float dy = (float)(y1 - y2), dx = (float)(x1 - x2);
                float dist = sqrtf(dy * dy + dx * dx);
                float pen = 1.0f - fminf(dist / DIST_THR_F, 1.0f);
                float v = fmaxf(acc[mi][nj][r], 0.0f) * invA * invB3[nj] * pen;
                vals[nj] = v;
                sum3 += v;
            }
#pragma unroll
            for (int m = 1; m <= 8; m <<= 1) sum3 += __shfl_xor(sum3, m, 64);
            if (r16 == 0) atomicAdd(&rsum[il], sum3);
#pragma unroll
            for (int nj = 0; nj < 3; nj++) {
                int col = ct * 96 + w * 48 + nj * 16 + r16;
                unsigned short o = (hi || col == ti) ? (unsigned short)0 : f2bf(vals[nj]);
                prow[col] = o;
            }
        }
    }
    __syncthreads();
    if (tid < 48) atomicAdd(&rowsum[b * K_ + rt * 48 + tid], rsum[tid]);
}

// ---------------- Kernel 3: aggregation GEMM, fused transpose + normalize + self ----
// (unchanged)
__global__ __launch_bounds__(384) void k_agg5(const unsigned short* __restrict__ bwn,
                                              const float* __restrict__ agg,
                                              const int* __restrict__ bench_idx,
                                              const float* __restrict__ rowsum,
                                              float* __restrict__ out) {
    __shared__ unsigned short LA[144 * 64];
    __shared__ unsigned int   LB[256 * 32];     // [d][32 u32 of j-pairs]
    int bid  = blockIdx.x;
    int xcd  = bid & 7;
    int s    = bid >> 3;               // 0..31
    int dt   = s & 3;
    int b    = (s >> 2) * 8 + xcd;
    int tid  = threadIdx.x;
    int w = tid >> 6, lane = tid & 63, g = lane >> 4, r16 = lane & 15;
    int wr = w >> 1, wc = w & 1;       // rows wr*48, d-cols wc*128

    const unsigned short* asrc[3];
    int adso[3];
#pragma unroll
    for (int q = 0; q < 3; q++) {
        int cid = tid + 384 * q;
        int row = cid >> 3, p = cid & 7, l = p ^ (row & 7);
        asrc[q] = bwn + (size_t)(b * K_ + row) * N_ + l * 8;
        adso[q] = row * 64 + p * 8;
    }
    const float* bbase = agg + (size_t)b * N_ * D_ + dt * 256 + lane * 4;

    bf16x8 areg[3];
    float4 breg[6][2];
#pragma unroll
    for (int q = 0; q < 3; q++) areg[q] = *(const bf16x8*)(asrc[q]);
#pragma unroll
    for (int u = 0; u < 6; u++) {
        int pp = w + 6 * u;
        if (pp < 32) {
            breg[u][0] = *(const float4*)(bbase + (size_t)(2 * pp) * D_);
            breg[u][1] = *(const float4*)(bbase + (size_t)(2 * pp + 1) * D_);
        }
    }

    f32x4 acc[3][8] = {};

    for (int t = 0; t < 9; ++t) {
#pragma unroll
        for (int q = 0; q < 3; q++) *(bf16x8*)&LA[adso[q]] = areg[q];
#pragma unroll
        for (int u = 0; u < 6; u++) {
            int pp = w + 6 * u;
            if (pp < 32) {
                float a0[4] = { breg[u][0].x, breg[u][0].y, breg[u][0].z, breg[u][0].w };
                float a1[4] = { breg[u][1].x, breg[u][1].y, breg[u][1].z, breg[u][1].w };
                int js = pp >> 2;
#pragma unroll
                for (int c = 0; c < 4; c++) {
                    int d = lane * 4 + c;
                    int sw = (js ^ (d & 7) ^ ((d >> 3) & 7)) & 7;
                    unsigned pk = (unsigned)f2bf(a0[c]) | ((unsigned)f2bf(a1[c]) << 16);
                    LB[d * 32 + sw * 4 + (pp & 3)] = pk;
                }
            }
        }
        __syncthreads();
        if (t < 8) {
            int kb = (t + 1) * 64;
#pragma unroll
            for (int q = 0; q < 3; q++) areg[q] = *(const bf16x8*)(asrc[q] + kb);
#pragma unroll
            for (int u = 0; u < 6; u++) {
                int pp = w + 6 * u;
                if (pp < 32) {
                    breg[u][0] = *(const float4*)(bbase + (size_t)(kb + 2 * pp) * D_);
                    breg[u][1] = *(const float4*)(bbase + (size_t)(kb + 2 * pp + 1) * D_);
                }
            }
        }
#pragma unroll
        for (int h = 0; h < 2; h++) {
            int ks = h * 4 + g;
            bf16x8 af[3], bf[8];
#pragma unroll
            for (int mi = 0; mi < 3; mi++) {
                int row = wr * 48 + mi * 16 + r16;
                af[mi] = *(const bf16x8*)&LA[row * 64 + (ks ^ (row & 7)) * 8];
            }
#pragma unroll
            for (int nj = 0; nj < 8; nj++) {
                int d = wc * 128 + nj * 16 + r16;
                int sw = (ks ^ (d & 7) ^ ((d >> 3) & 7)) & 7;
                bf[nj] = *(const bf16x8*)&LB[d * 32 + sw * 4];
            }
#pragma unroll
            for (int mi = 0; mi < 3; mi++)
#pragma unroll
                for (int nj = 0; nj < 8; nj++)
                    acc[mi][nj] = __builtin_amdgcn_mfma_f32_16x16x32_bf16(af[mi], bf[nj], acc[mi][nj], 0, 0, 0);
        }
        __syncthreads();
    }

#pragma unroll
    for (int mi = 0; mi < 3; mi++) {
#pragma unroll
        for (int r = 0; r < 4; r++) {
            int i = wr * 48 + mi * 16 + g * 4 + r;
            float S = rowsum[b * K_ + i];
            float sc = 1.0f / (S + 1e-8f);
            int ti = bench_idx[b * K_ + i];
            const float* selfrow = agg + (size_t)(b * N_ + ti) * D_ + dt * 256 + wc * 128;
            float* orow = out + (size_t)(b * K_ + i) * D_ + dt * 256 + wc * 128;
#pragma unroll
            for (int nj = 0; nj < 8; nj++)
                orow[nj * 16 + r16] = acc[mi][nj][r] * sc + selfrow[nj * 16 + r16];
        }
    }
}

extern "C" void kernel_launch(void* const* d_in, const int* in_sizes, int n_in,
                              void* d_out, int out_size, void* d_ws, size_t ws_size,
                              hipStream_t stream) {
    const float* hs_agg = (const float*)d_in[0];
    const float* hs_sim = (const float*)d_in[1];
    const float* metric = (const float*)d_in[2];
    float* out = (float*)d_out;
    char* ws = (char*)d_ws;

    const size_t BWN_BYTES = (size_t)B_ * K_ * N_ * 2;    // 10,616,832
    unsigned short* bwn = (unsigned short*)ws;
    int*   bench_idx = (int*)(ws + BWN_BYTES);
    int*   high      = (int*)(ws + BWN_BYTES + (size_t)B_ * K_ * 4);
    float* rowsum    = (float*)(ws + BWN_BYTES + (size_t)B_ * K_ * 8);
    float* out_idx   = out + (size_t)B_ * K_ * D_;

    hipLaunchKernelGGL(k_select, dim3(B_),      dim3(256), 0, stream, metric, bench_idx, high, out_idx, rowsum);
    hipLaunchKernelGGL(k_simf,   dim3(B_ * 18), dim3(128), 0, stream, hs_sim, bench_idx, high, bwn, rowsum);
    hipLaunchKernelGGL(k_agg5,   dim3(B_ * 4),  dim3(384), 0, stream, bwn, hs_agg, bench_idx, rowsum, out);
}

// Round 20
// 105.582 us; speedup vs baseline: 1.2611x; 1.2611x over previous
//
#include <hip/hip_runtime.h>
#include <hip/hip_bf16.h>
#include <stdint.h>

#define B_  64
#define N_  576
#define D_  1024
#define K_  144
#define HW_ 24
#define DIST_THR_F 16.733200530681511f

using bf16x8 = __attribute__((ext_vector_type(8))) short;
using f32x4  = __attribute__((ext_vector_type(4))) float;

__device__ __forceinline__ unsigned short f2bf(float f) {
    unsigned u = __float_as_uint(f);
    u += 0x7fffu + ((u >> 16) & 1u);
    return (unsigned short)(u >> 16);
}

// ---------------- Kernel 1: fused cast+norms (blocks 0..2303) + select (2304..) -----
// ROUND-20: cast role uses 16B/lane STORES (bf16x8) — every prior variant stored
// 8B/lane (ushort4), half the coalescing sweet spot on the write stream. Each lane
// owns 8 consecutive f32: 2x float4 load -> cvt -> one 16B store (issues
// immediately; no reduce dependency). Raw bf16 + invn (round-17-verified algebra).
__global__ __launch_bounds__(256) void k_prep4(const float* __restrict__ x,
                                               unsigned short* __restrict__ pn,
                                               float* __restrict__ invn,
                                               const float* __restrict__ metric,
                                               int* __restrict__ bench_idx,
                                               int* __restrict__ high,
                                               float* __restrict__ out_idx,
                                               float* __restrict__ rowsum) {
    if (blockIdx.x < 2304) {
        int wv   = threadIdx.x >> 6;
        int lane = threadIdx.x & 63;
        int row  = blockIdx.x * 4 + wv;
        const float*    src = x  + (size_t)row * D_;
        unsigned short* dst = pn + (size_t)row * D_;
        float ss = 0.f;
#pragma unroll
        for (int h = 0; h < 2; h++) {
            int off = h * 512 + lane * 8;
            float4 a = *(const float4*)(src + off);
            float4 b = *(const float4*)(src + off + 4);
            ss += a.x*a.x + a.y*a.y + a.z*a.z + a.w*a.w
                + b.x*b.x + b.y*b.y + b.z*b.z + b.w*b.w;
            union { bf16x8 v; unsigned short u[8]; } pk;
            pk.u[0] = f2bf(a.x); pk.u[1] = f2bf(a.y); pk.u[2] = f2bf(a.z); pk.u[3] = f2bf(a.w);
            pk.u[4] = f2bf(b.x); pk.u[5] = f2bf(b.y); pk.u[6] = f2bf(b.z); pk.u[7] = f2bf(b.w);
            *reinterpret_cast<bf16x8*>(dst + off) = pk.v;   // 16B/lane store
        }
#pragma unroll
        for (int m = 32; m >= 1; m >>= 1) ss += __shfl_xor(ss, m, 64);
        if (lane == 0) invn[row] = 1.0f / fmaxf(sqrtf(ss), 1e-12f);
        return;
    }
    // ---------------- select role ----------------
    __shared__ float sm[N_];
    __shared__ float sc[512];
    __shared__ int   si[512];
    __shared__ unsigned smask[18];
    __shared__ int   wpref[18];
    __shared__ float thr_s;
    int b = blockIdx.x - 2304, tid = threadIdx.x;
    for (int i = tid; i < N_; i += 256) sm[i] = metric[b * N_ + i];
    if (tid < 18) smask[tid] = 0u;
    if (tid < 144) rowsum[b * K_ + tid] = 0.f;
    __syncthreads();
    if (tid < 144) {
        int ry = tid / 12, rx = tid - ry * 12;
        int base = ry * 48 + rx * 2;
        float vv[4] = { sm[base], sm[base + 1], sm[base + 24], sm[base + 25] };
        int   tk[4] = { base, base + 1, base + 24, base + 25 };
        int a0 = 0;
#pragma unroll
        for (int j = 1; j < 4; j++) if (vv[j] > vv[a0]) a0 = j;
        int a1 = -1;
#pragma unroll
        for (int j = 0; j < 4; j++) {
            if (j == a0) continue;
            if (a1 < 0 || vv[j] > vv[a1]) a1 = j;
        }
        sc[2 * tid]     = vv[a0]; si[2 * tid]     = tk[a0];
        sc[2 * tid + 1] = vv[a1]; si[2 * tid + 1] = tk[a1];
    }
    for (int i = 288 + tid; i < 512; i += 256) { sc[i] = -1e30f; si[i] = 0x7fffffff; }
    __syncthreads();
    for (int k = 2; k <= 512; k <<= 1) {
        for (int j = k >> 1; j > 0; j >>= 1) {
#pragma unroll 2
            for (int t = tid; t < 512; t += 256) {
                int ixj = t ^ j;
                if (ixj > t) {
                    float s1 = sc[t], s2 = sc[ixj];
                    int   i1 = si[t], i2 = si[ixj];
                    bool before = (s1 > s2) || (s1 == s2 && i1 < i2);
                    bool up = ((t & k) == 0);
                    if (up ? !before : before) {
                        sc[t] = s2; sc[ixj] = s1; si[t] = i2; si[ixj] = i1;
                    }
                }
            }
            __syncthreads();
        }
    }
    if (tid == 0) {
        float qpos = 0.55f * 143.0f;
        float g = qpos - 78.0f;
        thr_s = sc[65] * (1.0f - g) + sc[64] * g;
    }
    if (tid < 144) atomicOr(&smask[si[tid] >> 5], 1u << (si[tid] & 31));
    __syncthreads();
    if (tid == 0) {
        int acc = 0;
        for (int w = 0; w < 18; w++) { wpref[w] = acc; acc += __popc(smask[w]); }
    }
    __syncthreads();
    if (tid < 144) {
        int tok = si[tid], w = tok >> 5;
        int rank = wpref[w] + __popc(smask[w] & ((1u << (tok & 31)) - 1u));
        bench_idx[b * K_ + rank] = tok;
        high[b * K_ + rank] = (sc[tid] >= thr_s) ? 1 : 0;
        out_idx[b * K_ + rank] = (float)tok;
    }
}

// ---------------- Kernel 2: sim GEMM (raw bf16) + epilogue norms + penalty ----------
// (round-17 k_sim13 verbatim — measured-equal best bf16 sim)
__global__ __launch_bounds__(128) void k_sim13(const unsigned short* __restrict__ pn,
                                               const float* __restrict__ invn,
                                               const int* __restrict__ bench_idx,
                                               const int* __restrict__ high,
                                               unsigned short* __restrict__ bwn,
                                               float* __restrict__ rowsum) {
    __shared__ unsigned short SM[144 * 64];
    __shared__ float rsum[48];
    __shared__ float ivL[144];
    int bid  = blockIdx.x;
    int xcd  = bid & 7;
    int slot = bid >> 3;               // 0..143
    int s18  = slot % 18;
    int b    = (slot / 18) * 8 + xcd;
    int rt   = s18 / 6;                // row tile 0..2
    int ct   = s18 % 6;                // col tile 0..5
    int tid  = threadIdx.x;
    int w = tid >> 6, lane = tid & 63, g = lane >> 4, r16 = lane & 15;

    if (tid < 48) rsum[tid] = 0.f;
#pragma unroll
    for (int i = tid; i < 144; i += 128) {
        ivL[i] = (i < 48) ? invn[b * N_ + bench_idx[b * K_ + rt * 48 + i]]
                          : invn[b * N_ + ct * 96 + (i - 48)];
    }

    const unsigned short* pnb = pn + (size_t)b * N_ * D_;

    const unsigned short* gsrc[9];
    int dsoff[9];
#pragma unroll
    for (int q = 0; q < 9; q++) {
        int row = (tid >> 3) + 16 * q;  // 0..143
        int p   = tid & 7;
        int l   = p ^ (row & 7);
        int tok = (row < 48) ? bench_idx[b * K_ + rt * 48 + row] : (ct * 96 + (row - 48));
        gsrc[q]  = pnb + (size_t)tok * D_ + l * 8;
        dsoff[q] = row * 64 + p * 8;
    }

    bf16x8 sreg[9];
#pragma unroll
    for (int q = 0; q < 9; q++) sreg[q] = *(const bf16x8*)(gsrc[q]);

    f32x4 acc[3][3] = {};

    for (int t = 0; t < 16; ++t) {
#pragma unroll
        for (int q = 0; q < 9; q++) *(bf16x8*)&SM[dsoff[q]] = sreg[q];
        __syncthreads();
        if (t < 15) {
            int kb = (t + 1) * 64;
#pragma unroll
            for (int q = 0; q < 9; q++) sreg[q] = *(const bf16x8*)(gsrc[q] + kb);
        }
#pragma unroll
        for (int h = 0; h < 2; h++) {
            int ks = h * 4 + g;
            bf16x8 af[3], bf[3];
#pragma unroll
            for (int mi = 0; mi < 3; mi++) {
                int row = mi * 16 + r16;                       // A region rows 0..47
                af[mi] = *(const bf16x8*)&SM[row * 64 + (ks ^ (row & 7)) * 8];
            }
#pragma unroll
            for (int nj = 0; nj < 3; nj++) {
                int row = 48 + w * 48 + nj * 16 + r16;         // B region rows 48..143
                bf[nj] = *(const bf16x8*)&SM[row * 64 + (ks ^ (row & 7)) * 8];
            }
#pragma unroll
            for (int mi = 0; mi < 3; mi++)
#pragma unroll
                for (int nj = 0; nj < 3; nj++)
                    acc[mi][nj] = __builtin_amdgcn_mfma_f32_16x16x32_bf16(af[mi], bf[nj], acc[mi][nj], 0, 0, 0);
        }
        __syncthreads();
    }

    float invB3[3];
#pragma unroll
    for (int nj = 0; nj < 3; nj++)
        invB3[nj] = ivL[48 + w * 48 + nj * 16 + r16];
#pragma unroll
    for (int mi = 0; mi < 3; mi++) {
#pragma unroll
        for (int r = 0; r < 4; r++) {
            int il = mi * 16 + g * 4 + r;        // local row 0..47
            int i  = rt * 48 + il;
            int ti = bench_idx[b * K_ + i];
            int hi = high[b * K_ + i];
            float invA = ivL[il];
            int y1 = ti / HW_, x1 = ti % HW_;
            unsigned short* prow = bwn + (size_t)(b * K_ + i) * N_;
            float vals[3];
            float sum3 = 0.f;
#pragma unroll
            for (int nj = 0; nj < 3; nj++) {
                int col = ct * 96 + w * 48 + nj * 16 + r16;
                int y2 = col / HW_, x2 = col % HW_;
                float dy = (float)(y1 - y2), dx = (float)(x1 - x2);
                float dist = sqrtf(dy * dy + dx * dx);
                float pen = 1.0f - fminf(dist / DIST_THR_F, 1.0f);
                float v = fmaxf(acc[mi][nj][r], 0.0f) * invA * invB3[nj] * pen;
                vals[nj] = v;
                sum3 += v;
            }
#pragma unroll
            for (int m = 1; m <= 8; m <<= 1) sum3 += __shfl_xor(sum3, m, 64);
            if (r16 == 0) atomicAdd(&rsum[il], sum3);
#pragma unroll
            for (int nj = 0; nj < 3; nj++) {
                int col = ct * 96 + w * 48 + nj * 16 + r16;
                unsigned short o = (hi || col == ti) ? (unsigned short)0 : f2bf(vals[nj]);
                prow[col] = o;
            }
        }
    }
    __syncthreads();
    if (tid < 48) atomicAdd(&rowsum[b * K_ + rt * 48 + tid], rsum[tid]);
}

// ---------------- Kernel 3: aggregation GEMM, fused transpose + normalize + self ----
// (unchanged)
__global__ __launch_bounds__(384) void k_agg5(const unsigned short* __restrict__ bwn,
                                              const float* __restrict__ agg,
                                              const int* __restrict__ bench_idx,
                                              const float* __restrict__ rowsum,
                                              float* __restrict__ out) {
    __shared__ unsigned short LA[144 * 64];
    __shared__ unsigned int   LB[256 * 32];     // [d][32 u32 of j-pairs]
    int bid  = blockIdx.x;
    int xcd  = bid & 7;
    int s    = bid >> 3;               // 0..31
    int dt   = s & 3;
    int b    = (s >> 2) * 8 + xcd;
    int tid  = threadIdx.x;
    int w = tid >> 6, lane = tid & 63, g = lane >> 4, r16 = lane & 15;
    int wr = w >> 1, wc = w & 1;       // rows wr*48, d-cols wc*128

    const unsigned short* asrc[3];
    int adso[3];
#pragma unroll
    for (int q = 0; q < 3; q++) {
        int cid = tid + 384 * q;
        int row = cid >> 3, p = cid & 7, l = p ^ (row & 7);
        asrc[q] = bwn + (size_t)(b * K_ + row) * N_ + l * 8;
        adso[q] = row * 64 + p * 8;
    }
    const float* bbase = agg + (size_t)b * N_ * D_ + dt * 256 + lane * 4;

    bf16x8 areg[3];
    float4 breg[6][2];
#pragma unroll
    for (int q = 0; q < 3; q++) areg[q] = *(const bf16x8*)(asrc[q]);
#pragma unroll
    for (int u = 0; u < 6; u++) {
        int pp = w + 6 * u;
        if (pp < 32) {
            breg[u][0] = *(const float4*)(bbase + (size_t)(2 * pp) * D_);
            breg[u][1] = *(const float4*)(bbase + (size_t)(2 * pp + 1) * D_);
        }
    }

    f32x4 acc[3][8] = {};

    for (int t = 0; t < 9; ++t) {
#pragma unroll
        for (int q = 0; q < 3; q++) *(bf16x8*)&LA[adso[q]] = areg[q];
#pragma unroll
        for (int u = 0; u < 6; u++) {
            int pp = w + 6 * u;
            if (pp < 32) {
                float a0[4] = { breg[u][0].x, breg[u][0].y, breg[u][0].z, breg[u][0].w };
                float a1[4] = { breg[u][1].x, breg[u][1].y, breg[u][1].z, breg[u][1].w };
                int js = pp >> 2;
#pragma unroll
                for (int c = 0; c < 4; c++) {
                    int d = lane * 4 + c;
                    int sw = (js ^ (d & 7) ^ ((d >> 3) & 7)) & 7;
                    unsigned pk = (unsigned)f2bf(a0[c]) | ((unsigned)f2bf(a1[c]) << 16);
                    LB[d * 32 + sw * 4 + (pp & 3)] = pk;
                }
            }
        }
        __syncthreads();
        if (t < 8) {
            int kb = (t + 1) * 64;
#pragma unroll
            for (int q = 0; q < 3; q++) areg[q] = *(const bf16x8*)(asrc[q] + kb);
#pragma unroll
            for (int u = 0; u < 6; u++) {
                int pp = w + 6 * u;
                if (pp < 32) {
                    breg[u][0] = *(const float4*)(bbase + (size_t)(kb + 2 * pp) * D_);
                    breg[u][1] = *(const float4*)(bbase + (size_t)(kb + 2 * pp + 1) * D_);
                }
            }
        }
#pragma unroll
        for (int h = 0; h < 2; h++) {
            int ks = h * 4 + g;
            bf16x8 af[3], bf[8];
#pragma unroll
            for (int mi = 0; mi < 3; mi++) {
                int row = wr * 48 + mi * 16 + r16;
                af[mi] = *(const bf16x8*)&LA[row * 64 + (ks ^ (row & 7)) * 8];
            }
#pragma unroll
            for (int nj = 0; nj < 8; nj++) {
                int d = wc * 128 + nj * 16 + r16;
                int sw = (ks ^ (d & 7) ^ ((d >> 3) & 7)) & 7;
                bf[nj] = *(const bf16x8*)&LB[d * 32 + sw * 4];
            }
#pragma unroll
            for (int mi = 0; mi < 3; mi++)
#pragma unroll
                for (int nj = 0; nj < 8; nj++)
                    acc[mi][nj] = __builtin_amdgcn_mfma_f32_16x16x32_bf16(af[mi], bf[nj], acc[mi][nj], 0, 0, 0);
        }
        __syncthreads();
    }

#pragma unroll
    for (int mi = 0; mi < 3; mi++) {
#pragma unroll
        for (int r = 0; r < 4; r++) {
            int i = wr * 48 + mi * 16 + g * 4 + r;
            float S = rowsum[b * K_ + i];
            float sc = 1.0f / (S + 1e-8f);
            int ti = bench_idx[b * K_ + i];
            const float* selfrow = agg + (size_t)(b * N_ + ti) * D_ + dt * 256 + wc * 128;
            float* orow = out + (size_t)(b * K_ + i) * D_ + dt * 256 + wc * 128;
#pragma unroll
            for (int nj = 0; nj < 8; nj++)
                orow[nj * 16 + r16] = acc[mi][nj][r] * sc + selfrow[nj * 16 + r16];
        }
    }
}

extern "C" void kernel_launch(void* const* d_in, const int* in_sizes, int n_in,
                              void* d_out, int out_size, void* d_ws, size_t ws_size,
                              hipStream_t stream) {
    const float* hs_agg = (const float*)d_in[0];
    const float* hs_sim = (const float*)d_in[1];
    const float* metric = (const float*)d_in[2];
    float* out = (float*)d_out;
    char* ws = (char*)d_ws;

    const size_t PN_BYTES  = (size_t)B_ * N_ * D_ * 2;    // 75,497,472
    const size_t BWN_BYTES = (size_t)B_ * K_ * N_ * 2;    // 10,616,832
    unsigned short* pn  = (unsigned short*)ws;
    unsigned short* bwn = (unsigned short*)(ws + PN_BYTES);
    int*   bench_idx = (int*)(ws + PN_BYTES + BWN_BYTES);
    int*   high      = (int*)(ws + PN_BYTES + BWN_BYTES + (size_t)B_ * K_ * 4);
    float* rowsum    = (float*)(ws + PN_BYTES + BWN_BYTES + (size_t)B_ * K_ * 8);
    float* invnorm   = (float*)(ws + PN_BYTES + BWN_BYTES + (size_t)B_ * K_ * 12);
    float* out_idx   = out + (size_t)B_ * K_ * D_;

    hipLaunchKernelGGL(k_prep4, dim3(2304 + B_), dim3(256), 0, stream,
                       hs_sim, pn, invnorm, metric, bench_idx, high, out_idx, rowsum);
    hipLaunchKernelGGL(k_sim13, dim3(B_ * 18),   dim3(128), 0, stream,
                       pn, invnorm, bench_idx, high, bwn, rowsum);
    hipLaunchKernelGGL(k_agg5,  dim3(B_ * 4),    dim3(384), 0, stream,
                       bwn, hs_agg, bench_idx, rowsum, out);
}